// Round 1
// baseline (1582.581 us; speedup 1.0000x reference)
//
#include <hip/hip_runtime.h>
#include <hip/hip_bf16.h>

#define N_NODES 50000
#define N_EDGES 800000
#define F_IN 128
#define HC 256
#define HEADS 4
#define HID 64
#define N_GRAPHS 64
#define N_CLASSES 16

__device__ __forceinline__ float wave_sum(float v) {
    #pragma unroll
    for (int off = 32; off > 0; off >>= 1) v += __shfl_xor(v, off);
    return v;
}

// ---------------- small utility kernels ----------------

__global__ void zero_f32(float* __restrict__ p, int n) {
    int i = blockIdx.x * 256 + threadIdx.x;
    if (i < n) p[i] = 0.f;
}

__global__ void deg_init(int* __restrict__ deg, int n) {
    int i = blockIdx.x * 256 + threadIdx.x;
    if (i < n) deg[i] = 1;  // self-loop
}

__global__ void deg_count(const int* __restrict__ dst, int* __restrict__ deg, int E) {
    int e = blockIdx.x * 256 + threadIdx.x;
    if (e < E) atomicAdd(&deg[dst[e]], 1);
}

// single-block exclusive scan over n=50000 ints
__global__ __launch_bounds__(1024) void scan_kernel(const int* __restrict__ deg,
                                                    int* __restrict__ rowptr,
                                                    int* __restrict__ cursor, int n) {
    __shared__ int part[1024];
    int t = threadIdx.x;
    int chunk = (n + 1023) >> 10;
    int c0 = t * chunk, c1 = min(c0 + chunk, n);
    int s = 0;
    for (int i = c0; i < c1; ++i) s += deg[i];
    part[t] = s;
    __syncthreads();
    for (int off = 1; off < 1024; off <<= 1) {
        int u = (t >= off) ? part[t - off] : 0;
        __syncthreads();
        part[t] += u;
        __syncthreads();
    }
    int run = part[t] - s;  // exclusive prefix
    for (int i = c0; i < c1; ++i) {
        rowptr[i] = run; cursor[i] = run; run += deg[i];
    }
    if (t == 1023) rowptr[n] = part[1023];
}

__global__ void csr_fill(const int* __restrict__ src, const int* __restrict__ dst,
                         int* __restrict__ cursor, int* __restrict__ csr_src,
                         int* __restrict__ csr_eid, int E, int N) {
    int e = blockIdx.x * 256 + threadIdx.x;
    if (e >= E + N) return;
    int s, d;
    if (e < E) { s = src[e]; d = dst[e]; } else { s = d = e - E; }
    int pos = atomicAdd(&cursor[d], 1);
    csr_src[pos] = s;
    csr_eid[pos] = e;
}

// W [256, K] row-major -> Wt4 [K/4][256] of float4 (4 consecutive k packed)
__global__ void transpose_w(const float* __restrict__ W, float4* __restrict__ Wt4, int K) {
    int idx = blockIdx.x * 256 + threadIdx.x;
    int total = (K >> 2) * 256;
    if (idx >= total) return;
    int o = idx & 255, kc = idx >> 8;
    float4 v = *reinterpret_cast<const float4*>(W + (size_t)o * K + 4 * kc);
    Wt4[kc * 256 + o] = v;
}

// ---------------- FastKAN: LN -> RBF basis -> matmul, + attention logits ----------------
// 8 nodes per block, 256 threads. Each wave builds basis for 2 nodes; matmul phase
// has each thread own one output channel for all 8 nodes.
template <int IN>
__global__ __launch_bounds__(256) void fastkan_kernel(
    const float* __restrict__ xin, const float* __restrict__ ln_g, const float* __restrict__ ln_b,
    const float4* __restrict__ Wt4, const float* __restrict__ att_s, const float* __restrict__ att_d,
    float* __restrict__ hout, float* __restrict__ as_out, float* __restrict__ ad_out, int nnodes)
{
    constexpr int PER = IN / 64;
    __shared__ __align__(16) float bas[8][IN * 4];
    int t = threadIdx.x, lane = t & 63, w = t >> 6;
    int base = blockIdx.x * 8;

    #pragma unroll
    for (int jj = 0; jj < 2; ++jj) {
        int j = 2 * w + jj;
        int node = base + j;
        if (node < nnodes) {
            float xv[PER];
            float s = 0.f, sq = 0.f;
            #pragma unroll
            for (int i = 0; i < PER; ++i) {
                float v = xin[(size_t)node * IN + i * 64 + lane];
                xv[i] = v; s += v; sq += v * v;
            }
            s = wave_sum(s); sq = wave_sum(sq);
            float mean = s * (1.f / IN);
            float var = sq * (1.f / IN) - mean * mean;
            float rs = rsqrtf(var + 1e-5f);
            #pragma unroll
            for (int i = 0; i < PER; ++i) {
                int d = i * 64 + lane;
                float v = (xv[i] - mean) * rs * ln_g[d] + ln_b[d];
                float t0 = (v + 2.f) * 0.75f;
                float t1 = (v + 2.f / 3.f) * 0.75f;
                float t2 = (v - 2.f / 3.f) * 0.75f;
                float t3 = (v - 2.f) * 0.75f;
                float4 e4;
                e4.x = __expf(-t0 * t0); e4.y = __expf(-t1 * t1);
                e4.z = __expf(-t2 * t2); e4.w = __expf(-t3 * t3);
                reinterpret_cast<float4*>(bas[j])[d] = e4;
            }
        }
    }
    __syncthreads();

    float acc[8] = {};
    for (int kc = 0; kc < IN; ++kc) {
        float4 wv = Wt4[kc * 256 + t];
        #pragma unroll
        for (int j = 0; j < 8; ++j) {
            float4 bv = reinterpret_cast<const float4*>(bas[j])[kc];
            acc[j] = fmaf(bv.x, wv.x, acc[j]);
            acc[j] = fmaf(bv.y, wv.y, acc[j]);
            acc[j] = fmaf(bv.z, wv.z, acc[j]);
            acc[j] = fmaf(bv.w, wv.w, acc[j]);
        }
    }

    int head = t >> 6, c = t & 63;
    float va_s = att_s[head * 64 + c], va_d = att_d[head * 64 + c];
    #pragma unroll
    for (int j = 0; j < 8; ++j) {
        int node = base + j;
        if (node < nnodes) {
            hout[(size_t)node * 256 + t] = acc[j];
            float ps = wave_sum(acc[j] * va_s);
            float pd = wave_sum(acc[j] * va_d);
            if (lane == 0) {
                as_out[node * 4 + head] = ps;
                ad_out[node * 4 + head] = pd;
            }
        }
    }
}

// per-edge exp(leaky_relu(as[src]+ad[dst])) for all 4 heads (E real edges + N self loops)
__global__ void edge_ee(const int* __restrict__ src, const int* __restrict__ dst,
                        const float* __restrict__ as_, const float* __restrict__ ad_,
                        float* __restrict__ ee, int E, int N) {
    int e = blockIdx.x * 256 + threadIdx.x;
    if (e >= E + N) return;
    int s, d;
    if (e < E) { s = src[e]; d = dst[e]; } else { s = d = e - E; }
    float4 a = *reinterpret_cast<const float4*>(as_ + 4 * (size_t)s);
    float4 b = *reinterpret_cast<const float4*>(ad_ + 4 * (size_t)d);
    float4 r;
    float v;
    v = a.x + b.x; v = v > 0.f ? v : 0.2f * v; r.x = __expf(v);
    v = a.y + b.y; v = v > 0.f ? v : 0.2f * v; r.y = __expf(v);
    v = a.z + b.z; v = v > 0.f ? v : 0.2f * v; r.z = __expf(v);
    v = a.w + b.w; v = v > 0.f ? v : 0.2f * v; r.w = __expf(v);
    *reinterpret_cast<float4*>(ee + 4 * (size_t)e) = r;
}

// attention-weighted aggregation per dst node; fused bias + silu.
// MODE 0: write out[d]; MODE 1: atomicAdd into pooled[batch[d]]
template <int MODE>
__global__ __launch_bounds__(256) void gat_agg(
    const int* __restrict__ rowptr, const int* __restrict__ csr_src, const int* __restrict__ csr_eid,
    const float* __restrict__ ee, const float* __restrict__ h, const float* __restrict__ bias,
    float* __restrict__ out, const int* __restrict__ batch, float* __restrict__ pooled)
{
    int d = blockIdx.x, t = threadIdx.x, head = t >> 6;
    int r0 = rowptr[d], r1 = rowptr[d + 1];
    float acc = 0.f, se = 0.f;
    for (int r = r0; r < r1; ++r) {
        int s = csr_src[r];
        float ev = ee[(size_t)csr_eid[r] * 4 + head];
        acc = fmaf(ev, h[(size_t)s * 256 + t], acc);
        se += ev;
    }
    float val = acc / se + bias[t];
    val = val / (1.f + __expf(-val));  // silu
    if (MODE == 0) out[(size_t)d * 256 + t] = val;
    else atomicAdd(&pooled[batch[d] * 256 + t], val);
}

// readout: LN -> RBF -> [16] logits -> log_softmax, one block per graph
__global__ __launch_bounds__(256) void readout_kernel(
    const float* __restrict__ pooled, const float* __restrict__ ln_g, const float* __restrict__ ln_b,
    const float* __restrict__ Wr, float* __restrict__ out)
{
    __shared__ __align__(16) float bas[1024];
    __shared__ float red[8];
    __shared__ float part[16][17];
    int t = threadIdx.x, lane = t & 63, w = t >> 6;
    int g = blockIdx.x;
    float val = pooled[g * 256 + t];
    float s = wave_sum(val), sq = wave_sum(val * val);
    if (lane == 0) { red[w] = s; red[4 + w] = sq; }
    __syncthreads();
    float stot = red[0] + red[1] + red[2] + red[3];
    float sqtot = red[4] + red[5] + red[6] + red[7];
    float mean = stot * (1.f / 256), var = sqtot * (1.f / 256) - mean * mean;
    float rs = rsqrtf(var + 1e-5f);
    float v = (val - mean) * rs * ln_g[t] + ln_b[t];
    float t0 = (v + 2.f) * 0.75f;
    float t1 = (v + 2.f / 3.f) * 0.75f;
    float t2 = (v - 2.f / 3.f) * 0.75f;
    float t3 = (v - 2.f) * 0.75f;
    float4 e4;
    e4.x = __expf(-t0 * t0); e4.y = __expf(-t1 * t1);
    e4.z = __expf(-t2 * t2); e4.w = __expf(-t3 * t3);
    reinterpret_cast<float4*>(bas)[t] = e4;
    __syncthreads();
    int o = t & 15, slice = t >> 4;
    float p = 0.f;
    const float* wrow = Wr + o * 1024 + slice * 64;
    const float* brow = bas + slice * 64;
    #pragma unroll 8
    for (int kk = 0; kk < 64; ++kk) p = fmaf(brow[kk], wrow[kk], p);
    part[o][slice] = p;
    __syncthreads();
    if (t < 16) {
        float l = 0.f;
        #pragma unroll
        for (int s2 = 0; s2 < 16; ++s2) l += part[t][s2];
        float m = l;
        #pragma unroll
        for (int off = 8; off; off >>= 1) m = fmaxf(m, __shfl_xor(m, off));
        float ex = __expf(l - m);
        float ssum = ex;
        #pragma unroll
        for (int off = 8; off; off >>= 1) ssum += __shfl_xor(ssum, off);
        out[g * 16 + t] = l - m - logf(ssum);
    }
}

// ---------------- launch ----------------

extern "C" void kernel_launch(void* const* d_in, const int* in_sizes, int n_in,
                              void* d_out, int out_size, void* d_ws, size_t ws_size,
                              hipStream_t stream) {
    const float* x      = (const float*)d_in[0];
    const int*   edge   = (const int*)d_in[1];
    const int*   batch  = (const int*)d_in[2];
    const float* ln_g0  = (const float*)d_in[3];
    const float* ln_b0  = (const float*)d_in[4];
    const float* W0     = (const float*)d_in[5];
    const float* att_s0 = (const float*)d_in[6];
    const float* att_d0 = (const float*)d_in[7];
    const float* bias0  = (const float*)d_in[8];
    const float* ln_g1  = (const float*)d_in[9];
    const float* ln_b1  = (const float*)d_in[10];
    const float* W1     = (const float*)d_in[11];
    const float* att_s1 = (const float*)d_in[12];
    const float* att_d1 = (const float*)d_in[13];
    const float* bias1  = (const float*)d_in[14];
    const float* ln_gr  = (const float*)d_in[15];
    const float* ln_br  = (const float*)d_in[16];
    const float* Wr     = (const float*)d_in[17];
    float* outp = (float*)d_out;

    const int N = N_NODES, E = N_EDGES;
    const int* src = edge;
    const int* dst = edge + E;

    // workspace carve-up (floats, 64-float aligned)
    float* ws = (float*)d_ws;
    size_t off = 0;
    auto alloc = [&](size_t nf) { float* p = ws + off; off += (nf + 63) & ~(size_t)63; return p; };
    float* W0t    = alloc(512 * 256);
    float* W1t    = alloc(1024 * 256);
    float* h      = alloc((size_t)N * 256);
    float* xmid   = alloc((size_t)N * 256);
    float* as_    = alloc((size_t)N * 4);
    float* ad_    = alloc((size_t)N * 4);
    float* ee     = alloc((size_t)(E + N) * 4);
    int*   rowptr = (int*)alloc(N + 1);
    int*   cursor = (int*)alloc(N);
    int*   deg    = (int*)alloc(N);
    int*   csr_src= (int*)alloc(E + N);
    int*   csr_eid= (int*)alloc(E + N);
    float* pooled = alloc(N_GRAPHS * 256);

    // CSR build (graph identical both layers -> build once)
    deg_init<<<(N + 255) / 256, 256, 0, stream>>>(deg, N);
    deg_count<<<(E + 255) / 256, 256, 0, stream>>>(dst, deg, E);
    transpose_w<<<(512 / 4 * 256 + 255) / 256, 256, 0, stream>>>(W0, (float4*)W0t, 512);
    transpose_w<<<(1024 / 4 * 256 + 255) / 256, 256, 0, stream>>>(W1, (float4*)W1t, 1024);
    scan_kernel<<<1, 1024, 0, stream>>>(deg, rowptr, cursor, N);
    csr_fill<<<(E + N + 255) / 256, 256, 0, stream>>>(src, dst, cursor, csr_src, csr_eid, E, N);

    // layer 0
    fastkan_kernel<128><<<(N + 7) / 8, 256, 0, stream>>>(x, ln_g0, ln_b0, (const float4*)W0t,
                                                         att_s0, att_d0, h, as_, ad_, N);
    edge_ee<<<(E + N + 255) / 256, 256, 0, stream>>>(src, dst, as_, ad_, ee, E, N);
    gat_agg<0><<<N, 256, 0, stream>>>(rowptr, csr_src, csr_eid, ee, h, bias0, xmid, nullptr, nullptr);

    // layer 1
    fastkan_kernel<256><<<(N + 7) / 8, 256, 0, stream>>>(xmid, ln_g1, ln_b1, (const float4*)W1t,
                                                         att_s1, att_d1, h, as_, ad_, N);
    edge_ee<<<(E + N + 255) / 256, 256, 0, stream>>>(src, dst, as_, ad_, ee, E, N);
    zero_f32<<<(N_GRAPHS * 256 + 255) / 256, 256, 0, stream>>>(pooled, N_GRAPHS * 256);
    gat_agg<1><<<N, 256, 0, stream>>>(rowptr, csr_src, csr_eid, ee, h, bias1, nullptr, batch, pooled);

    // readout
    readout_kernel<<<N_GRAPHS, 256, 0, stream>>>(pooled, ln_gr, ln_br, Wr, outp);
}

// Round 2
// 787.299 us; speedup vs baseline: 2.0101x; 2.0101x over previous
//
#include <hip/hip_runtime.h>
#include <hip/hip_bf16.h>

#define N_NODES 50000
#define N_EDGES 800000
#define F_IN 128
#define HC 256
#define HEADS 4
#define HID 64
#define N_GRAPHS 64
#define N_CLASSES 16

typedef __attribute__((ext_vector_type(8))) short bfrag;    // 8 bf16 (4 VGPRs)
typedef __attribute__((ext_vector_type(4))) float f32x4;    // MFMA accumulator

__device__ __forceinline__ float wave_sum(float v) {
    #pragma unroll
    for (int off = 32; off > 0; off >>= 1) v += __shfl_xor(v, off);
    return v;
}

__device__ __forceinline__ unsigned int pack_bf2(float a, float b) {
    unsigned int ua = __bfloat16_as_ushort(__float2bfloat16(a));
    unsigned int ub = __bfloat16_as_ushort(__float2bfloat16(b));
    return ua | (ub << 16);
}

// ---------------- small utility kernels ----------------

__global__ void zero_f32(float* __restrict__ p, int n) {
    int i = blockIdx.x * 256 + threadIdx.x;
    if (i < n) p[i] = 0.f;
}

__global__ void deg_init(int* __restrict__ deg, int n) {
    int i = blockIdx.x * 256 + threadIdx.x;
    if (i < n) deg[i] = 1;  // self-loop
}

__global__ void deg_count(const int* __restrict__ dst, int* __restrict__ deg, int E) {
    int e = blockIdx.x * 256 + threadIdx.x;
    if (e < E) atomicAdd(&deg[dst[e]], 1);
}

// single-block exclusive scan over n=50000 ints
__global__ __launch_bounds__(1024) void scan_kernel(const int* __restrict__ deg,
                                                    int* __restrict__ rowptr,
                                                    int* __restrict__ cursor, int n) {
    __shared__ int part[1024];
    int t = threadIdx.x;
    int chunk = (n + 1023) >> 10;
    int c0 = t * chunk, c1 = min(c0 + chunk, n);
    int s = 0;
    for (int i = c0; i < c1; ++i) s += deg[i];
    part[t] = s;
    __syncthreads();
    for (int off = 1; off < 1024; off <<= 1) {
        int u = (t >= off) ? part[t - off] : 0;
        __syncthreads();
        part[t] += u;
        __syncthreads();
    }
    int run = part[t] - s;  // exclusive prefix
    for (int i = c0; i < c1; ++i) {
        rowptr[i] = run; cursor[i] = run; run += deg[i];
    }
    if (t == 1023) rowptr[n] = part[1023];
}

// fill csr_src; record pos_of[e] so edge_ee can write attention coefs in CSR order
__global__ void csr_fill(const int* __restrict__ src, const int* __restrict__ dst,
                         int* __restrict__ cursor, int* __restrict__ csr_src,
                         int* __restrict__ pos_of, int E, int N) {
    int e = blockIdx.x * 256 + threadIdx.x;
    if (e >= E + N) return;
    int s, d;
    if (e < E) { s = src[e]; d = dst[e]; } else { s = d = e - E; }
    int pos = atomicAdd(&cursor[d], 1);
    csr_src[pos] = s;
    pos_of[e] = pos;
}

// elementwise f32 -> bf16 (weights), n multiple of 4
__global__ void convert_w(const float* __restrict__ W, __hip_bfloat16* __restrict__ Wb, int n) {
    int i4 = (blockIdx.x * 256 + threadIdx.x) * 4;
    if (i4 >= n) return;
    float4 v = *reinterpret_cast<const float4*>(W + i4);
    ushort2 lo, hi;
    lo.x = __bfloat16_as_ushort(__float2bfloat16(v.x));
    lo.y = __bfloat16_as_ushort(__float2bfloat16(v.y));
    hi.x = __bfloat16_as_ushort(__float2bfloat16(v.z));
    hi.y = __bfloat16_as_ushort(__float2bfloat16(v.w));
    ushort4 o; o.x = lo.x; o.y = lo.y; o.z = hi.x; o.w = hi.y;
    *reinterpret_cast<ushort4*>(Wb + i4) = o;
}

// ---------------- FastKAN via MFMA ----------------
// 32 nodes/block, 256 threads (4 waves). Wave w owns output cols [64w,64w+64) = head w.
// Basis (LN -> RBF) staged in LDS as bf16, row-major [32][K], XOR-swizzled (byte ^= (row&7)<<4).
// Matmul: mfma_f32_16x16x32_bf16, A = basis tile (LDS), B = W rows (global, L2-resident).
template <int IN>
__global__ __launch_bounds__(256) void fastkan_mfma(
    const float* __restrict__ xin, const float* __restrict__ ln_g, const float* __restrict__ ln_b,
    const __hip_bfloat16* __restrict__ Wb, const float* __restrict__ att_s, const float* __restrict__ att_d,
    __hip_bfloat16* __restrict__ hout, float* __restrict__ as_out, float* __restrict__ ad_out, int nnodes)
{
    constexpr int K  = IN * 4;   // bf16 elements per basis row
    constexpr int RB = K * 2;    // row bytes (1024 or 2048)
    constexpr int DPL = IN / 64; // input dims per lane (2 or 4)
    __shared__ __align__(16) unsigned char bas[32 * RB];

    int t = threadIdx.x, lane = t & 63, w = t >> 6;
    int lc = lane & 15, lr = lane >> 4;
    int base = blockIdx.x * 32;

    // ---- basis phase: wave w fills rows 8w..8w+7 ----
    for (int j = 0; j < 8; ++j) {
        int r = w * 8 + j;
        int node = base + r;
        unsigned char* rowp = bas + r * RB;
        int swz = (r & 7) << 4;
        if (node < nnodes) {
            float xv[DPL];
            const float* xr = xin + (size_t)node * IN + DPL * lane;
            if constexpr (DPL == 2) {
                float2 v2 = *reinterpret_cast<const float2*>(xr);
                xv[0] = v2.x; xv[1] = v2.y;
            } else {
                float4 v4 = *reinterpret_cast<const float4*>(xr);
                xv[0] = v4.x; xv[1] = v4.y; xv[2] = v4.z; xv[3] = v4.w;
            }
            float s = 0.f, sq = 0.f;
            #pragma unroll
            for (int i = 0; i < DPL; ++i) { s += xv[i]; sq += xv[i] * xv[i]; }
            s = wave_sum(s); sq = wave_sum(sq);
            float mean = s * (1.f / IN);
            float var  = sq * (1.f / IN) - mean * mean;
            float rs = rsqrtf(var + 1e-5f);
            unsigned int pk[DPL * 2];
            #pragma unroll
            for (int i = 0; i < DPL; ++i) {
                int d = DPL * lane + i;
                float v = (xv[i] - mean) * rs * ln_g[d] + ln_b[d];
                float t0 = (v + 2.f) * 0.75f;
                float t1 = (v + 2.f / 3.f) * 0.75f;
                float t2 = (v - 2.f / 3.f) * 0.75f;
                float t3 = (v - 2.f) * 0.75f;
                float e0 = __expf(-t0 * t0), e1 = __expf(-t1 * t1);
                float e2 = __expf(-t2 * t2), e3 = __expf(-t3 * t3);
                pk[2 * i]     = pack_bf2(e0, e1);
                pk[2 * i + 1] = pack_bf2(e2, e3);
            }
            #pragma unroll
            for (int q = 0; q < DPL / 2; ++q) {
                uint4 u; u.x = pk[4 * q]; u.y = pk[4 * q + 1]; u.z = pk[4 * q + 2]; u.w = pk[4 * q + 3];
                *reinterpret_cast<uint4*>(rowp + ((lane * DPL * 8 + q * 16) ^ swz)) = u;
            }
        } else {
            uint4 z{};
            #pragma unroll
            for (int q = 0; q < DPL / 2; ++q)
                *reinterpret_cast<uint4*>(rowp + ((lane * DPL * 8 + q * 16) ^ swz)) = z;
        }
    }
    __syncthreads();

    // ---- MFMA phase: wave w -> rows {0-15,16-31} x cols {64w..64w+63} ----
    f32x4 acc[2][4] = {};
    // A fragment: row = mf*16 + lc, k = ks*32 + lr*8 + i  (8 consecutive k per lane)
    // B fragment: col n = 64w + nf*16 + lc, same k         (8 consecutive k of W row n)
    const unsigned char* ap = bas + lc * RB;       // mf=0 row; mf=1 at +16*RB (same swizzle: (16+lc)&7 == lc&7)
    int aswz = (lc & 7) << 4;
    const __hip_bfloat16* wbase = Wb + (size_t)(w * 64 + lc) * K + lr * 8;

    #pragma unroll 4
    for (int ks = 0; ks < K / 32; ++ks) {
        int boff = (ks * 64 + lr * 16);
        bfrag a0 = *reinterpret_cast<const bfrag*>(ap + (boff ^ aswz));
        bfrag a1 = *reinterpret_cast<const bfrag*>(ap + 16 * RB + (boff ^ aswz));
        #pragma unroll
        for (int nf = 0; nf < 4; ++nf) {
            bfrag b = *reinterpret_cast<const bfrag*>(wbase + (size_t)nf * 16 * K + ks * 32);
            acc[0][nf] = __builtin_amdgcn_mfma_f32_16x16x32_bf16(a0, b, acc[0][nf], 0, 0, 0);
            acc[1][nf] = __builtin_amdgcn_mfma_f32_16x16x32_bf16(a1, b, acc[1][nf], 0, 0, 0);
        }
    }

    // ---- epilogue: C/D layout col=lane&15, row=(lane>>4)*4+reg (m89-verified) ----
    float asw[4], adw[4];
    #pragma unroll
    for (int nf = 0; nf < 4; ++nf) {
        asw[nf] = att_s[w * 64 + nf * 16 + lc];
        adw[nf] = att_d[w * 64 + nf * 16 + lc];
    }
    #pragma unroll
    for (int mf = 0; mf < 2; ++mf) {
        #pragma unroll
        for (int reg = 0; reg < 4; ++reg) {
            int node = base + mf * 16 + lr * 4 + reg;
            bool ok = node < nnodes;
            float ps = 0.f, pd = 0.f;
            #pragma unroll
            for (int nf = 0; nf < 4; ++nf) {
                float v = acc[mf][nf][reg];
                ps = fmaf(v, asw[nf], ps);
                pd = fmaf(v, adw[nf], pd);
                if (ok) hout[(size_t)node * 256 + w * 64 + nf * 16 + lc] = __float2bfloat16(v);
            }
            // reduce across the 16 lanes of this row-group (xor 1,2,4,8 stays in-group)
            #pragma unroll
            for (int off = 8; off; off >>= 1) {
                ps += __shfl_xor(ps, off);
                pd += __shfl_xor(pd, off);
            }
            if (ok && lc == 0) {
                as_out[node * 4 + w] = ps;
                ad_out[node * 4 + w] = pd;
            }
        }
    }
}

// per-edge exp(leaky_relu(as[src]+ad[dst])), written directly in CSR order
__global__ void edge_ee(const int* __restrict__ src, const int* __restrict__ dst,
                        const int* __restrict__ pos_of,
                        const float* __restrict__ as_, const float* __restrict__ ad_,
                        float* __restrict__ ee_csr, int E, int N) {
    int e = blockIdx.x * 256 + threadIdx.x;
    if (e >= E + N) return;
    int s, d;
    if (e < E) { s = src[e]; d = dst[e]; } else { s = d = e - E; }
    float4 a = *reinterpret_cast<const float4*>(as_ + 4 * (size_t)s);
    float4 b = *reinterpret_cast<const float4*>(ad_ + 4 * (size_t)d);
    float4 r; float v;
    v = a.x + b.x; v = v > 0.f ? v : 0.2f * v; r.x = __expf(v);
    v = a.y + b.y; v = v > 0.f ? v : 0.2f * v; r.y = __expf(v);
    v = a.z + b.z; v = v > 0.f ? v : 0.2f * v; r.z = __expf(v);
    v = a.w + b.w; v = v > 0.f ? v : 0.2f * v; r.w = __expf(v);
    reinterpret_cast<float4*>(ee_csr)[pos_of[e]] = r;
}

// attention-weighted aggregation per dst node (bf16 h gather, unroll-4 for ILP);
// fused bias + silu. MODE 0: write out[d] (f32); MODE 1: atomicAdd into pooled[batch[d]]
template <int MODE>
__global__ __launch_bounds__(256) void gat_agg(
    const int* __restrict__ rowptr, const int* __restrict__ csr_src,
    const float* __restrict__ ee_csr, const __hip_bfloat16* __restrict__ h,
    const float* __restrict__ bias, float* __restrict__ out,
    const int* __restrict__ batch, float* __restrict__ pooled)
{
    int d = blockIdx.x, t = threadIdx.x, head = t >> 6;
    int r0 = rowptr[d], r1 = rowptr[d + 1];
    float acc = 0.f, se = 0.f;
    int r = r0;
    for (; r + 4 <= r1; r += 4) {
        int s0 = csr_src[r], s1 = csr_src[r + 1], s2 = csr_src[r + 2], s3 = csr_src[r + 3];
        float e0 = ee_csr[4 * r + head],        e1 = ee_csr[4 * (r + 1) + head];
        float e2 = ee_csr[4 * (r + 2) + head],  e3 = ee_csr[4 * (r + 3) + head];
        float h0 = __bfloat162float(h[(size_t)s0 * 256 + t]);
        float h1 = __bfloat162float(h[(size_t)s1 * 256 + t]);
        float h2 = __bfloat162float(h[(size_t)s2 * 256 + t]);
        float h3 = __bfloat162float(h[(size_t)s3 * 256 + t]);
        acc = fmaf(e0, h0, acc); acc = fmaf(e1, h1, acc);
        acc = fmaf(e2, h2, acc); acc = fmaf(e3, h3, acc);
        se += (e0 + e1) + (e2 + e3);
    }
    for (; r < r1; ++r) {
        int s = csr_src[r];
        float ev = ee_csr[4 * r + head];
        acc = fmaf(ev, __bfloat162float(h[(size_t)s * 256 + t]), acc);
        se += ev;
    }
    float val = acc / se + bias[t];
    val = val / (1.f + __expf(-val));  // silu
    if (MODE == 0) out[(size_t)d * 256 + t] = val;
    else atomicAdd(&pooled[batch[d] * 256 + t], val);
}

// readout: LN -> RBF -> [16] logits -> log_softmax, one block per graph
__global__ __launch_bounds__(256) void readout_kernel(
    const float* __restrict__ pooled, const float* __restrict__ ln_g, const float* __restrict__ ln_b,
    const float* __restrict__ Wr, float* __restrict__ out)
{
    __shared__ __align__(16) float bas[1024];
    __shared__ float red[8];
    __shared__ float part[16][17];
    int t = threadIdx.x, lane = t & 63, w = t >> 6;
    int g = blockIdx.x;
    float val = pooled[g * 256 + t];
    float s = wave_sum(val), sq = wave_sum(val * val);
    if (lane == 0) { red[w] = s; red[4 + w] = sq; }
    __syncthreads();
    float stot = red[0] + red[1] + red[2] + red[3];
    float sqtot = red[4] + red[5] + red[6] + red[7];
    float mean = stot * (1.f / 256), var = sqtot * (1.f / 256) - mean * mean;
    float rs = rsqrtf(var + 1e-5f);
    float v = (val - mean) * rs * ln_g[t] + ln_b[t];
    float t0 = (v + 2.f) * 0.75f;
    float t1 = (v + 2.f / 3.f) * 0.75f;
    float t2 = (v - 2.f / 3.f) * 0.75f;
    float t3 = (v - 2.f) * 0.75f;
    float4 e4;
    e4.x = __expf(-t0 * t0); e4.y = __expf(-t1 * t1);
    e4.z = __expf(-t2 * t2); e4.w = __expf(-t3 * t3);
    reinterpret_cast<float4*>(bas)[t] = e4;
    __syncthreads();
    int o = t & 15, slice = t >> 4;
    float p = 0.f;
    const float* wrow = Wr + o * 1024 + slice * 64;
    const float* brow = bas + slice * 64;
    #pragma unroll 8
    for (int kk = 0; kk < 64; ++kk) p = fmaf(brow[kk], wrow[kk], p);
    part[o][slice] = p;
    __syncthreads();
    if (t < 16) {
        float l = 0.f;
        #pragma unroll
        for (int s2 = 0; s2 < 16; ++s2) l += part[t][s2];
        float m = l;
        #pragma unroll
        for (int off = 8; off; off >>= 1) m = fmaxf(m, __shfl_xor(m, off));
        float ex = __expf(l - m);
        float ssum = ex;
        #pragma unroll
        for (int off = 8; off; off >>= 1) ssum += __shfl_xor(ssum, off);
        out[g * 16 + t] = l - m - logf(ssum);
    }
}

// ---------------- launch ----------------

extern "C" void kernel_launch(void* const* d_in, const int* in_sizes, int n_in,
                              void* d_out, int out_size, void* d_ws, size_t ws_size,
                              hipStream_t stream) {
    const float* x      = (const float*)d_in[0];
    const int*   edge   = (const int*)d_in[1];
    const int*   batch  = (const int*)d_in[2];
    const float* ln_g0  = (const float*)d_in[3];
    const float* ln_b0  = (const float*)d_in[4];
    const float* W0     = (const float*)d_in[5];
    const float* att_s0 = (const float*)d_in[6];
    const float* att_d0 = (const float*)d_in[7];
    const float* bias0  = (const float*)d_in[8];
    const float* ln_g1  = (const float*)d_in[9];
    const float* ln_b1  = (const float*)d_in[10];
    const float* W1     = (const float*)d_in[11];
    const float* att_s1 = (const float*)d_in[12];
    const float* att_d1 = (const float*)d_in[13];
    const float* bias1  = (const float*)d_in[14];
    const float* ln_gr  = (const float*)d_in[15];
    const float* ln_br  = (const float*)d_in[16];
    const float* Wr     = (const float*)d_in[17];
    float* outp = (float*)d_out;

    const int N = N_NODES, E = N_EDGES;
    const int* src = edge;
    const int* dst = edge + E;

    // workspace carve-up (bytes, 256B aligned)
    unsigned char* ws = (unsigned char*)d_ws;
    size_t off = 0;
    auto alloc = [&](size_t nbytes) {
        unsigned char* p = ws + off;
        off += (nbytes + 255) & ~(size_t)255;
        return (void*)p;
    };
    __hip_bfloat16* W0b  = (__hip_bfloat16*)alloc(256 * 512 * 2);
    __hip_bfloat16* W1b  = (__hip_bfloat16*)alloc(256 * 1024 * 2);
    __hip_bfloat16* h_bf = (__hip_bfloat16*)alloc((size_t)N * 256 * 2);
    float* xmid   = (float*)alloc((size_t)N * 256 * 4);
    float* as_    = (float*)alloc((size_t)N * 4 * 4);
    float* ad_    = (float*)alloc((size_t)N * 4 * 4);
    float* ee_csr = (float*)alloc((size_t)(E + N) * 4 * 4);
    int*   rowptr = (int*)alloc((N + 1) * 4);
    int*   cursor = (int*)alloc(N * 4);
    int*   deg    = (int*)alloc(N * 4);
    int*   csr_src= (int*)alloc((size_t)(E + N) * 4);
    int*   pos_of = (int*)alloc((size_t)(E + N) * 4);
    float* pooled = (float*)alloc(N_GRAPHS * 256 * 4);

    // CSR build (graph identical both layers -> build once) + weight conversion
    deg_init<<<(N + 255) / 256, 256, 0, stream>>>(deg, N);
    deg_count<<<(E + 255) / 256, 256, 0, stream>>>(dst, deg, E);
    convert_w<<<(256 * 512 / 4 + 255) / 256, 256, 0, stream>>>(W0, W0b, 256 * 512);
    convert_w<<<(256 * 1024 / 4 + 255) / 256, 256, 0, stream>>>(W1, W1b, 256 * 1024);
    scan_kernel<<<1, 1024, 0, stream>>>(deg, rowptr, cursor, N);
    csr_fill<<<(E + N + 255) / 256, 256, 0, stream>>>(src, dst, cursor, csr_src, pos_of, E, N);

    // layer 0
    fastkan_mfma<128><<<(N + 31) / 32, 256, 0, stream>>>(x, ln_g0, ln_b0, W0b,
                                                         att_s0, att_d0, h_bf, as_, ad_, N);
    edge_ee<<<(E + N + 255) / 256, 256, 0, stream>>>(src, dst, pos_of, as_, ad_, ee_csr, E, N);
    gat_agg<0><<<N, 256, 0, stream>>>(rowptr, csr_src, ee_csr, h_bf, bias0, xmid, nullptr, nullptr);

    // layer 1
    fastkan_mfma<256><<<(N + 31) / 32, 256, 0, stream>>>(xmid, ln_g1, ln_b1, W1b,
                                                         att_s1, att_d1, h_bf, as_, ad_, N);
    edge_ee<<<(E + N + 255) / 256, 256, 0, stream>>>(src, dst, pos_of, as_, ad_, ee_csr, E, N);
    zero_f32<<<(N_GRAPHS * 256 + 255) / 256, 256, 0, stream>>>(pooled, N_GRAPHS * 256);
    gat_agg<1><<<N, 256, 0, stream>>>(rowptr, csr_src, ee_csr, h_bf, bias1, nullptr, batch, pooled);

    // readout
    readout_kernel<<<N_GRAPHS, 256, 0, stream>>>(pooled, ln_gr, ln_br, Wr, outp);
}